// Round 1
// baseline (302.750 us; speedup 1.0000x reference)
//
#include <hip/hip_runtime.h>

#define T_ 1000
#define B_ 64
#define V_ 1024
#define LMAX_ 64
#define EM_STRIDE 66            // 65 used floats per (b,t) row, padded
#define NEGF (-1e30f)

// log(exp(x)+exp(y)) in fp32, matching jnp.logaddexp with finite -1e30 sentinel.
__device__ __forceinline__ float lae(float x, float y) {
    float m = fmaxf(x, y);
    float d = fminf(x, y) - m;          // <= 0 (0 if both equal, incl. both NEG)
    return m + __logf(1.0f + __expf(d));
}

// Build padded per-sample targets: tgt_full[b][l] = targets[offset_b + l] if l < L_b else 0
__global__ void prep_tgt_k(const int* __restrict__ targets,
                           const int* __restrict__ tlen,
                           int* __restrict__ tgt_full) {
    int b = threadIdx.x;
    if (b >= B_) return;
    int off = 0;
    for (int i = 0; i < b; ++i) off += tlen[i];
    int L = tlen[b];
    for (int l = 0; l < LMAX_; ++l)
        tgt_full[b * LMAX_ + l] = (l < L) ? targets[off + l] : 0;
}

// em[b][t][0] = lp[t,b,0] (blank), em[b][t][1+i] = lp[t,b,tgt_full[b][i]]
__global__ __launch_bounds__(256) void gather_k(const float* __restrict__ lp,
                                                const int* __restrict__ tgt_full,
                                                const int* __restrict__ ilen,
                                                float* __restrict__ em) {
    int g = blockIdx.x * 256 + threadIdx.x;
    int i = g & 63;
    int tb = g >> 6;
    int t = tb % T_;
    int b = tb / T_;
    if (b >= B_) return;
    if (t >= ilen[b]) return;                       // rows past input length never read
    int col = tgt_full[b * LMAX_ + i];
    const float* row = lp + (size_t)t * (B_ * V_) + (size_t)b * V_;
    float* erow = em + ((size_t)b * T_ + t) * EM_STRIDE;
    erow[1 + i] = row[col];
    if (i == 0) erow[0] = row[0];
}

// One wave per sample. Lane i owns states s=2i (blank) and s=2i+1 (label i);
// lane 63 additionally owns state 128 (final blank).
__global__ __launch_bounds__(64) void ctc_rec_k(const float* __restrict__ srcbase,
                                                const int* __restrict__ tgt_full,
                                                const int* __restrict__ ilen,
                                                const int* __restrict__ tlen,
                                                float* __restrict__ losses,
                                                int mode) {
    int b = blockIdx.x;
    int lane = threadIdx.x;
    int L = tlen[b];
    int Tin = ilen[b];
    int tg = tgt_full[b * LMAX_ + lane];

    const float* src;
    long long stride;
    int colL;
    if (mode == 0) {                     // compact em buffer
        src = srcbase + (size_t)b * T_ * EM_STRIDE;
        stride = EM_STRIDE;
        colL = 1 + lane;
    } else {                             // direct gather fallback (small ws)
        src = srcbase + (size_t)b * V_;
        stride = (long long)B_ * V_;
        colL = tg;
    }

    int tgp = __shfl_up(tg, 1);
    // allow_skip for odd state 2i+1: i>=1, label nonzero, label != previous label
    bool skip1 = (lane >= 1) && (tg != 0) && (tg != tgp);

    // t = 0 init
    float blank0 = src[0];
    float e0 = src[colL];
    float a0 = (lane == 0) ? blank0 : NEGF;                    // even states
    float a1 = (lane == 0 && L > 0) ? e0 : NEGF;               // odd states
    float a2 = NEGF;                                           // state 128 (lane 63)

    int Te = Tin - 1;                                          // last time index

    auto step = [&](float xb, float xe) {
        float p1 = __shfl_up(a1, 1);
        float p1m = (lane >= 1) ? p1 : NEGF;                   // alpha[s-1] for even s=2i
        float na0 = lae(a0, p1m) + xb;                         // even state (no skip ever)
        float t1 = lae(a1, a0);                                // odd: alpha[s] + alpha[s-1]
        float na1 = lae(t1, skip1 ? p1m : NEGF) + xe;          // + skip path
        float na2 = lae(a2, a1) + xb;                          // state 128 (valid on lane 63)
        a0 = na0; a1 = na1; a2 = na2;
    };

    if (Te >= 1) {
        auto ldp = [&](int tt, float& xb, float& xe) {
            int tc = tt;
            if (tc > Te) tc = Te;                              // clamp: value unused, stay in-bounds
            const float* o = src + (long long)tc * stride;
            xb = o[0];
            xe = o[colL];
        };
        float qb0, qe0, qb1, qe1, qb2, qe2, qb3, qe3;
        ldp(1, qb0, qe0); ldp(2, qb1, qe1); ldp(3, qb2, qe2); ldp(4, qb3, qe3);
        int t = 1;
        while (t + 3 <= Te) {
            float nb0, ne0, nb1, ne1, nb2, ne2, nb3, ne3;
            ldp(t + 4, nb0, ne0); ldp(t + 5, nb1, ne1);
            ldp(t + 6, nb2, ne2); ldp(t + 7, nb3, ne3);
            step(qb0, qe0); step(qb1, qe1); step(qb2, qe2); step(qb3, qe3);
            qb0 = nb0; qe0 = ne0; qb1 = nb1; qe1 = ne1;
            qb2 = nb2; qe2 = ne2; qb3 = nb3; qe3 = ne3;
            t += 4;
        }
        if (t <= Te) { step(qb0, qe0); ++t; }
        if (t <= Te) { step(qb1, qe1); ++t; }
        if (t <= Te) { step(qb2, qe2); ++t; }
    }

    // end_ll at t = Tin-1 (alpha currently holds that step; Tin==1 -> alpha0)
    int lidx = (L > 0) ? (L - 1) : 0;
    float aPrev = __shfl(a1, lidx);
    int li2 = (L < 63) ? L : 63;
    float aLastEven = __shfl(a0, li2);
    float aLast = (L >= 64) ? __shfl(a2, 63) : aLastEven;
    float fin = lae(aLast, (L > 0) ? aPrev : NEGF);
    if (Tin <= 0) fin = NEGF;

    if (lane == 0) {
        float loss = (L > 0) ? -fin : 0.0f;
        if (!(loss < 1e29f)) loss = 0.0f;                      // zero_infinity (NaN-safe)
        losses[b] = loss;
    }
}

__global__ __launch_bounds__(64) void finalize_k(const float* __restrict__ losses,
                                                 const int* __restrict__ gid,
                                                 float* __restrict__ out) {
    int lane = threadIdx.x;
    float l = losses[lane];
    int g = gid[lane];
    float s = l;
    float s0 = (g == 0) ? l : 0.0f, c0 = (g == 0) ? 1.0f : 0.0f;
    float s1 = (g == 1) ? l : 0.0f, c1 = (g == 1) ? 1.0f : 0.0f;
    for (int off = 32; off; off >>= 1) {
        s  += __shfl_xor(s, off);
        s0 += __shfl_xor(s0, off);
        c0 += __shfl_xor(c0, off);
        s1 += __shfl_xor(s1, off);
        c1 += __shfl_xor(c1, off);
    }
    if (lane == 0) {
        float base = s * (1.0f / B_);
        float m0 = s0 / fmaxf(c0, 1.0f);
        float m1 = s1 / fmaxf(c1, 1.0f);
        float mean = 0.5f * (m0 + m1);
        float var = (m0 - mean) * (m0 - mean) + (m1 - mean) * (m1 - mean); // ddof=1, N=2
        out[0] = base + 0.5f * var;
        out[1] = base;
        out[2] = var;
    }
}

extern "C" void kernel_launch(void* const* d_in, const int* in_sizes, int n_in,
                              void* d_out, int out_size, void* d_ws, size_t ws_size,
                              hipStream_t stream) {
    const float* lp = (const float*)d_in[0];
    const int* targets = (const int*)d_in[1];
    const int* ilen = (const int*)d_in[2];
    const int* tlen = (const int*)d_in[3];
    const int* gid = (const int*)d_in[4];
    float* out = (float*)d_out;

    char* ws = (char*)d_ws;
    int* tgt_full = (int*)ws;                       // 16 KB
    float* losses = (float*)(ws + 16384);           // 256 B
    float* em = (float*)(ws + 32768);               // B*T*66 floats = 16.9 MB
    size_t need = 32768 + (size_t)B_ * T_ * EM_STRIDE * sizeof(float);
    int mode = (ws_size >= need) ? 0 : 1;

    prep_tgt_k<<<1, 64, 0, stream>>>(targets, tlen, tgt_full);
    if (mode == 0) {
        int total = B_ * T_ * 64;
        gather_k<<<total / 256, 256, 0, stream>>>(lp, tgt_full, ilen, em);
        ctc_rec_k<<<B_, 64, 0, stream>>>(em, tgt_full, ilen, tlen, losses, 0);
    } else {
        ctc_rec_k<<<B_, 64, 0, stream>>>(lp, tgt_full, ilen, tlen, losses, 1);
    }
    finalize_k<<<1, 64, 0, stream>>>(losses, gid, out);
}

// Round 2
// 225.702 us; speedup vs baseline: 1.3414x; 1.3414x over previous
//
#include <hip/hip_runtime.h>

#define T_ 1000
#define T4_ 250
#define B_ 64
#define V_ 1024
#define LMAX_ 64
#define NEGF (-1e30f)

// 2-way log-add-exp, fp32, matching jnp.logaddexp with finite -1e30 sentinel.
__device__ __forceinline__ float lae2(float x, float y) {
    float m = fmaxf(x, y);
    float d = fminf(x, y) - m;              // <= 0
    return m + __logf(1.0f + __expf(d));
}

// 3-way log-add-exp: max3 + 2 parallel exps + 1 log. All-NEG stays NEG (fp32 ulp @1e30 ~1e21).
__device__ __forceinline__ float lae3(float x, float y, float z) {
    float m = fmaxf(fmaxf(x, y), z);        // v_max3_f32
    float s = __expf(x - m) + __expf(y - m) + __expf(z - m);
    return m + __logf(s);
}

__global__ void prep_tgt_k(const int* __restrict__ targets,
                           const int* __restrict__ tlen,
                           int* __restrict__ tgt_full) {
    int b = threadIdx.x;
    if (b >= B_) return;
    int off = 0;
    for (int i = 0; i < b; ++i) off += tlen[i];
    int L = tlen[b];
    for (int l = 0; l < LMAX_; ++l)
        tgt_full[b * LMAX_ + l] = (l < L) ? targets[off + l] : 0;
}

// Blocked-transposed emission gather:
//   em4[((b*250 + t4)*64 + lane)*4 + (t&3)] = lp[t, b, tgt_full[b][lane]]
//   blk[b*1000 + t] = lp[t, b, 0]
// block = (b, t4), thread = tl*64 + i  -> each block writes 4KB contiguous.
__global__ __launch_bounds__(256) void gather_k(const float* __restrict__ lp,
                                                const int* __restrict__ tgt_full,
                                                const int* __restrict__ ilen,
                                                float* __restrict__ em4f,
                                                float* __restrict__ blk) {
    int t4 = blockIdx.x % T4_;
    int b = blockIdx.x / T4_;
    int tl = threadIdx.x >> 6;
    int i = threadIdx.x & 63;
    int t = t4 * 4 + tl;
    if (t >= ilen[b]) return;
    const float* row = lp + (size_t)t * (B_ * V_) + (size_t)b * V_;
    int col = tgt_full[b * LMAX_ + i];
    em4f[(((size_t)b * T4_ + t4) * 64 + i) * 4 + tl] = row[col];
    if (i == 0) blk[b * T_ + t] = row[0];
}

// One wave per sample; lane i owns states 2i (blank) and 2i+1 (label i); lane 63 also state 128.
__global__ __launch_bounds__(64) void ctc_rec_k(const float4* __restrict__ em4,
                                                const float4* __restrict__ blk4,
                                                const int* __restrict__ tgt_full,
                                                const int* __restrict__ ilen,
                                                const int* __restrict__ tlen,
                                                float* __restrict__ losses) {
    int b = blockIdx.x;
    int lane = threadIdx.x;
    int L = tlen[b];
    int Tin = ilen[b];
    int Te = Tin - 1;
    int tg = tgt_full[b * LMAX_ + lane];
    int tgp = __shfl_up(tg, 1);
    bool skip1 = (lane >= 1) && (tg != 0) && (tg != tgp);

    const float4* e4 = em4 + (size_t)b * T4_ * 64 + lane;   // stride 64 float4 per group
    const float4* b4 = blk4 + (size_t)b * (T_ / 4);         // uniform per wave

    int NG = (Te >> 2) + 1;          // groups containing any step t<=Te (incl. t=0)
    int Gc = NG - 1;

    auto ldE = [&](int g) -> float4 { int gc = g < Gc ? g : Gc; return e4[(size_t)gc * 64]; };
    auto ldB = [&](int g) -> float4 { int gc = g < Gc ? g : Gc; return b4[gc]; };

    float a0, a1, a2;                 // even state 2i, odd state 2i+1, state 128 (lane 63)

    auto step = [&](float xb, float xe) {
        float p1 = __shfl_up(a1, 1);
        float p1m = (lane >= 1) ? p1 : NEGF;      // alpha[s-1] for even s=2i
        float na0 = lae2(a0, p1m) + xb;
        float na1 = lae3(a1, a0, skip1 ? p1m : NEGF) + xe;
        float na2 = lae2(a2, a1) + xb;
        a0 = na0; a1 = na1; a2 = na2;
    };

#define PROC(EV, BV, GG) do {                                              \
        int tb_ = (GG) << 2;                                               \
        if (tb_ >= 1 && tb_ + 3 <= Te) {                                   \
            step(BV.x, EV.x); step(BV.y, EV.y);                            \
            step(BV.z, EV.z); step(BV.w, EV.w);                            \
        } else {                                                           \
            if (tb_ + 0 >= 1 && tb_ + 0 <= Te) step(BV.x, EV.x);           \
            if (tb_ + 1 >= 1 && tb_ + 1 <= Te) step(BV.y, EV.y);           \
            if (tb_ + 2 >= 1 && tb_ + 2 <= Te) step(BV.z, EV.z);           \
            if (tb_ + 3 >= 1 && tb_ + 3 <= Te) step(BV.w, EV.w);           \
        }                                                                  \
    } while (0)

    // preload groups 0..3
    float4 E0 = ldE(0), E1 = ldE(1), E2 = ldE(2), E3 = ldE(3);
    float4 B0 = ldB(0), B1 = ldB(1), B2 = ldB(2), B3 = ldB(3);

    // t = 0 init
    a0 = (lane == 0) ? B0.x : NEGF;
    a1 = (lane == 0 && L > 0) ? E0.x : NEGF;
    a2 = NEGF;

    for (int g = 0; g < NG; g += 4) {
        float4 N0 = ldE(g + 4), N1 = ldE(g + 5), N2 = ldE(g + 6), N3 = ldE(g + 7);
        float4 C0 = ldB(g + 4), C1 = ldB(g + 5), C2 = ldB(g + 6), C3 = ldB(g + 7);
        PROC(E0, B0, g);
        PROC(E1, B1, g + 1);
        PROC(E2, B2, g + 2);
        PROC(E3, B3, g + 3);
        E0 = N0; E1 = N1; E2 = N2; E3 = N3;
        B0 = C0; B1 = C1; B2 = C2; B3 = C3;
    }
#undef PROC

    // end_ll at t = Tin-1
    int lidx = (L > 0) ? (L - 1) : 0;
    float aPrev = __shfl(a1, lidx);
    int li2 = (L < 63) ? L : 63;
    float aLastEven = __shfl(a0, li2);
    float aLast = (L >= 64) ? __shfl(a2, 63) : aLastEven;
    float fin = lae2(aLast, (L > 0) ? aPrev : NEGF);
    if (Tin <= 0) fin = NEGF;

    if (lane == 0) {
        float loss = (L > 0) ? -fin : 0.0f;
        if (!(loss < 1e29f)) loss = 0.0f;         // zero_infinity (NaN-safe)
        losses[b] = loss;
    }
}

// Fallback when ws too small: direct per-step scattered loads from lp (slow, correct).
__global__ __launch_bounds__(64) void ctc_rec_direct_k(const float* __restrict__ lp,
                                                       const int* __restrict__ tgt_full,
                                                       const int* __restrict__ ilen,
                                                       const int* __restrict__ tlen,
                                                       float* __restrict__ losses) {
    int b = blockIdx.x;
    int lane = threadIdx.x;
    int L = tlen[b];
    int Tin = ilen[b];
    int tg = tgt_full[b * LMAX_ + lane];
    int tgp = __shfl_up(tg, 1);
    bool skip1 = (lane >= 1) && (tg != 0) && (tg != tgp);
    const float* src = lp + (size_t)b * V_;
    const long long stride = (long long)B_ * V_;

    float a0 = (lane == 0) ? src[0] : NEGF;
    float a1 = (lane == 0 && L > 0) ? src[tg] : NEGF;
    float a2 = NEGF;
    for (int t = 1; t < Tin; ++t) {
        const float* o = src + (long long)t * stride;
        float xb = o[0], xe = o[tg];
        float p1 = __shfl_up(a1, 1);
        float p1m = (lane >= 1) ? p1 : NEGF;
        float na0 = lae2(a0, p1m) + xb;
        float na1 = lae3(a1, a0, skip1 ? p1m : NEGF) + xe;
        float na2 = lae2(a2, a1) + xb;
        a0 = na0; a1 = na1; a2 = na2;
    }
    int lidx = (L > 0) ? (L - 1) : 0;
    float aPrev = __shfl(a1, lidx);
    int li2 = (L < 63) ? L : 63;
    float aLastEven = __shfl(a0, li2);
    float aLast = (L >= 64) ? __shfl(a2, 63) : aLastEven;
    float fin = lae2(aLast, (L > 0) ? aPrev : NEGF);
    if (Tin <= 0) fin = NEGF;
    if (lane == 0) {
        float loss = (L > 0) ? -fin : 0.0f;
        if (!(loss < 1e29f)) loss = 0.0f;
        losses[b] = loss;
    }
}

__global__ __launch_bounds__(64) void finalize_k(const float* __restrict__ losses,
                                                 const int* __restrict__ gid,
                                                 float* __restrict__ out) {
    int lane = threadIdx.x;
    float l = losses[lane];
    int g = gid[lane];
    float s = l;
    float s0 = (g == 0) ? l : 0.0f, c0 = (g == 0) ? 1.0f : 0.0f;
    float s1 = (g == 1) ? l : 0.0f, c1 = (g == 1) ? 1.0f : 0.0f;
    for (int off = 32; off; off >>= 1) {
        s  += __shfl_xor(s, off);
        s0 += __shfl_xor(s0, off);
        c0 += __shfl_xor(c0, off);
        s1 += __shfl_xor(s1, off);
        c1 += __shfl_xor(c1, off);
    }
    if (lane == 0) {
        float base = s * (1.0f / B_);
        float m0 = s0 / fmaxf(c0, 1.0f);
        float m1 = s1 / fmaxf(c1, 1.0f);
        float mean = 0.5f * (m0 + m1);
        float var = (m0 - mean) * (m0 - mean) + (m1 - mean) * (m1 - mean); // ddof=1, N=2
        out[0] = base + 0.5f * var;
        out[1] = base;
        out[2] = var;
    }
}

extern "C" void kernel_launch(void* const* d_in, const int* in_sizes, int n_in,
                              void* d_out, int out_size, void* d_ws, size_t ws_size,
                              hipStream_t stream) {
    const float* lp = (const float*)d_in[0];
    const int* targets = (const int*)d_in[1];
    const int* ilen = (const int*)d_in[2];
    const int* tlen = (const int*)d_in[3];
    const int* gid = (const int*)d_in[4];
    float* out = (float*)d_out;

    char* ws = (char*)d_ws;
    int* tgt_full = (int*)ws;                         // 16 KB
    float* losses = (float*)(ws + 16384);             // 256 B
    float* blk = (float*)(ws + 32768);                // B*T*4 = 256 KB
    float* em4f = (float*)(ws + 294912);              // B*250*64*16 = 16.38 MB (16B-aligned)
    size_t need = 294912 + (size_t)B_ * T4_ * 64 * 16;

    prep_tgt_k<<<1, 64, 0, stream>>>(targets, tlen, tgt_full);
    if (ws_size >= need) {
        gather_k<<<B_ * T4_, 256, 0, stream>>>(lp, tgt_full, ilen, em4f, blk);
        ctc_rec_k<<<B_, 64, 0, stream>>>((const float4*)em4f, (const float4*)blk,
                                         tgt_full, ilen, tlen, losses);
    } else {
        ctc_rec_direct_k<<<B_, 64, 0, stream>>>(lp, tgt_full, ilen, tlen, losses);
    }
    finalize_k<<<1, 64, 0, stream>>>(losses, gid, out);
}

// Round 5
// 116.508 us; speedup vs baseline: 2.5985x; 1.9372x over previous
//
#include <hip/hip_runtime.h>

#define T_ 1000
#define T4_ 250
#define B_ 64
#define V_ 1024
#define LMAX_ 64
#define NEGF (-1e30f)
#define LOG2E_ 1.4426950408889634f
#define LN2_ 0.6931471805599453f

__device__ __forceinline__ float ex2(float x) { return __builtin_amdgcn_exp2f(x); }
__device__ __forceinline__ float lg2(float x) { return __builtin_amdgcn_logf(x); }
__device__ __forceinline__ float rlane(float x, int l) {
    return __int_as_float(__builtin_amdgcn_readlane(__float_as_int(x), l));
}
#define FENCE_ __builtin_amdgcn_sched_barrier(0)

__global__ void prep_tgt_k(const int* __restrict__ targets,
                           const int* __restrict__ tlen,
                           int* __restrict__ tgt_full) {
    int b = threadIdx.x;
    if (b >= B_) return;
    int off = 0;
    for (int i = 0; i < b; ++i) off += tlen[i];
    int L = tlen[b];
    for (int l = 0; l < LMAX_; ++l)
        tgt_full[b * LMAX_ + l] = (l < L) ? targets[off + l] : 0;
}

// em4[((b*250+t4)*64+lane)*4 + (t&3)] = log2e * lp[t, b, lane<63 ? tgt[lane] : BLANK]
// (L <= 63 always, so lane 63's odd state never contributes; its slot carries the blank.)
__global__ __launch_bounds__(256) void gather_k(const float* __restrict__ lp,
                                                const int* __restrict__ tgt_full,
                                                const int* __restrict__ ilen,
                                                float* __restrict__ em4f) {
    int t4 = blockIdx.x % T4_;
    int b = blockIdx.x / T4_;
    int tl = threadIdx.x >> 6;
    int i = threadIdx.x & 63;
    int t = t4 * 4 + tl;
    if (t >= ilen[b]) return;
    int col = (i == 63) ? 0 : tgt_full[b * LMAX_ + i];
    const float* row = lp + (size_t)t * (B_ * V_) + (size_t)b * V_;
    em4f[(((size_t)b * T4_ + t4) * 64 + i) * 4 + tl] = row[col] * LOG2E_;
}

// One wave per sample. Lane i owns states 2i (blank) and 2i+1 (label i). L<=63.
__global__ __launch_bounds__(64) void ctc_rec_k(const float4* __restrict__ em4,
                                                const int* __restrict__ tgt_full,
                                                const int* __restrict__ ilen,
                                                const int* __restrict__ tlen,
                                                float* __restrict__ losses) {
    int b = blockIdx.x, lane = threadIdx.x;
    int L = tlen[b], Tin = ilen[b], Te = Tin - 1;
    int tg = tgt_full[b * LMAX_ + lane];
    int tgp = __shfl_up(tg, 1);
    bool skip1 = (lane >= 1) && (tg != 0) && (tg != tgp);
    bool row0 = (lane & 15) == 0;         // lanes 0,16,32,48
    bool is16 = (lane == 16), is32 = (lane == 32), is48 = (lane == 48);
    const float4* e4 = em4 + (size_t)b * (T4_ * 64) + lane;
    int Gc = Te >> 2;
    if (Gc < 0) Gc = 0;
    if (Gc > T4_ - 1) Gc = T4_ - 1;
    float a0 = NEGF, a1 = NEGF;

    auto ldE = [&](int g) -> float4 {
        int gm = g < Gc ? g : Gc;
        return e4[(size_t)gm * 64];
    };
    // p1m[lane] = a1[lane-1], p1m[0] = NEGF. row_shr:1 (row-local, CDNA-supported)
    // + readlane fixups for the 3 cross-row boundaries (row_bcast15 is DEAD on gfx90a+).
    auto shr1 = [&](float x) -> float {
        int xi = __float_as_int(x);
        float sh = __int_as_float(
            __builtin_amdgcn_update_dpp(__float_as_int(NEGF), xi, 0x111, 0xF, 0xF, false));
        float v15 = rlane(x, 15), v31 = rlane(x, 31), v47 = rlane(x, 47);
        float bval = is16 ? v15 : (is32 ? v31 : (is48 ? v47 : NEGF));  // lane 0 -> NEGF
        return row0 ? bval : sh;
    };
    auto step = [&](float xb, float xe) {
        float p1m = shr1(a1);
        float sk = skip1 ? p1m : NEGF;
        float m0 = fmaxf(a0, p1m);
        float d0 = fminf(a0, p1m) - m0;
        float na0 = m0 + lg2(1.0f + ex2(d0)) + xb;
        float m1 = fmaxf(fmaxf(a1, a0), sk);
        float s = ex2(a1 - m1) + ex2(a0 - m1) + ex2(sk - m1);
        float na1 = m1 + lg2(s) + xe;
        a0 = na0; a1 = na1;
    };

    if (Te >= 35) {
        float4 S0 = ldE(0), S1 = ldE(1), S2 = ldE(2), S3 = ldE(3);
        float4 S4 = ldE(4), S5 = ldE(5), S6 = ldE(6), S7 = ldE(7);
        FENCE_;
        // t = 0..3 from S0, then refill S0 <- group 8
        a0 = (lane == 0) ? rlane(S0.x, 63) : NEGF;
        a1 = (lane == 0 && L > 0) ? S0.x : NEGF;
        step(rlane(S0.y, 63), S0.y); step(rlane(S0.z, 63), S0.z); step(rlane(S0.w, 63), S0.w);
        S0 = ldE(8);
        FENCE_;
#define SUBF(S, G) do {                                                        \
        float xb0_ = rlane(S.x, 63), xb1_ = rlane(S.y, 63);                    \
        float xb2_ = rlane(S.z, 63), xb3_ = rlane(S.w, 63);                    \
        step(xb0_, S.x); step(xb1_, S.y); step(xb2_, S.z); step(xb3_, S.w);    \
        S = ldE((G) + 8);                                                      \
        FENCE_;                                                                \
    } while (0)
        SUBF(S1, 1); SUBF(S2, 2); SUBF(S3, 3); SUBF(S4, 4);
        SUBF(S5, 5); SUBF(S6, 6); SUBF(S7, 7);
        int c = 1;
        for (; 32 * c + 31 <= Te; ++c) {
            int g0 = 8 * c;
            SUBF(S0, g0 + 0); SUBF(S1, g0 + 1); SUBF(S2, g0 + 2); SUBF(S3, g0 + 3);
            SUBF(S4, g0 + 4); SUBF(S5, g0 + 5); SUBF(S6, g0 + 6); SUBF(S7, g0 + 7);
        }
#undef SUBF
        int tb = 32 * c;
#define SUBT(S, T0) do {                                                       \
        float xb0_ = rlane(S.x, 63), xb1_ = rlane(S.y, 63);                    \
        float xb2_ = rlane(S.z, 63), xb3_ = rlane(S.w, 63);                    \
        if ((T0) + 0 <= Te) step(xb0_, S.x);                                   \
        if ((T0) + 1 <= Te) step(xb1_, S.y);                                   \
        if ((T0) + 2 <= Te) step(xb2_, S.z);                                   \
        if ((T0) + 3 <= Te) step(xb3_, S.w);                                   \
    } while (0)
        SUBT(S0, tb + 0);  SUBT(S1, tb + 4);  SUBT(S2, tb + 8);  SUBT(S3, tb + 12);
        SUBT(S4, tb + 16); SUBT(S5, tb + 20); SUBT(S6, tb + 24); SUBT(S7, tb + 28);
#undef SUBT
    } else {
        // small-Te path (never hit with Tin>=500, kept for safety)
        float4 E0 = e4[0];
        a0 = (lane == 0) ? rlane(E0.x, 63) : NEGF;
        a1 = (lane == 0 && L > 0) ? E0.x : NEGF;
        for (int g = 0; 4 * g <= Te; ++g) {
            int gm = g < Gc ? g : Gc;
            float4 E = e4[(size_t)gm * 64];
            if (4 * g + 0 <= Te && 4 * g + 0 >= 1) step(rlane(E.x, 63), E.x);
            if (4 * g + 1 <= Te && 4 * g + 1 >= 1) step(rlane(E.y, 63), E.y);
            if (4 * g + 2 <= Te && 4 * g + 2 >= 1) step(rlane(E.z, 63), E.z);
            if (4 * g + 3 <= Te && 4 * g + 3 >= 1) step(rlane(E.w, 63), E.w);
        }
    }

    // end_ll at t = Tin-1 (log2 domain)
    int lidx = (L > 0) ? (L - 1) : 0;
    float aPrev = __shfl(a1, lidx);
    int li2 = (L < 63) ? L : 63;
    float aLast = __shfl(a0, li2);             // state 2L (even/blank), L<=63
    float x = aLast, y = (L > 0) ? aPrev : NEGF;
    float m = fmaxf(x, y), d = fminf(x, y) - m;
    float fin = m + lg2(1.0f + ex2(d));
    if (Tin <= 0) fin = NEGF;
    if (lane == 0) {
        float loss = (L > 0) ? -fin * LN2_ : 0.0f;
        if (!(loss < 1e29f)) loss = 0.0f;      // zero_infinity (NaN-safe)
        losses[b] = loss;
    }
}

// Fallback when ws too small: per-step scattered loads (slow, correct).
__global__ __launch_bounds__(64) void ctc_rec_direct_k(const float* __restrict__ lp,
                                                       const int* __restrict__ tgt_full,
                                                       const int* __restrict__ ilen,
                                                       const int* __restrict__ tlen,
                                                       float* __restrict__ losses) {
    int b = blockIdx.x, lane = threadIdx.x;
    int L = tlen[b], Tin = ilen[b], Te = Tin - 1;
    int tg = tgt_full[b * LMAX_ + lane];
    int tgp = __shfl_up(tg, 1);
    bool skip1 = (lane >= 1) && (tg != 0) && (tg != tgp);
    bool row0 = (lane & 15) == 0;
    bool is16 = (lane == 16), is32 = (lane == 32), is48 = (lane == 48);
    int col = (lane == 63) ? 0 : tg;
    const float* src = lp + (size_t)b * V_;
    const long long stride = (long long)B_ * V_;
    float a0 = NEGF, a1 = NEGF;
    auto shr1 = [&](float x) -> float {
        int xi = __float_as_int(x);
        float sh = __int_as_float(
            __builtin_amdgcn_update_dpp(__float_as_int(NEGF), xi, 0x111, 0xF, 0xF, false));
        float v15 = rlane(x, 15), v31 = rlane(x, 31), v47 = rlane(x, 47);
        float bval = is16 ? v15 : (is32 ? v31 : (is48 ? v47 : NEGF));
        return row0 ? bval : sh;
    };
    auto step = [&](float xb, float xe) {
        float p1m = shr1(a1);
        float sk = skip1 ? p1m : NEGF;
        float m0 = fmaxf(a0, p1m);
        float d0 = fminf(a0, p1m) - m0;
        float na0 = m0 + lg2(1.0f + ex2(d0)) + xb;
        float m1 = fmaxf(fmaxf(a1, a0), sk);
        float s = ex2(a1 - m1) + ex2(a0 - m1) + ex2(sk - m1);
        float na1 = m1 + lg2(s) + xe;
        a0 = na0; a1 = na1;
    };
    if (Tin >= 1) {
        float e = src[col] * LOG2E_;
        a0 = (lane == 0) ? rlane(e, 63) : NEGF;
        a1 = (lane == 0 && L > 0) ? e : NEGF;
        for (int t = 1; t <= Te; ++t) {
            float xe = src[(long long)t * stride + col] * LOG2E_;
            step(rlane(xe, 63), xe);
        }
    }
    int lidx = (L > 0) ? (L - 1) : 0;
    float aPrev = __shfl(a1, lidx);
    int li2 = (L < 63) ? L : 63;
    float aLast = __shfl(a0, li2);
    float x = aLast, y = (L > 0) ? aPrev : NEGF;
    float m = fmaxf(x, y), d = fminf(x, y) - m;
    float fin = m + lg2(1.0f + ex2(d));
    if (Tin <= 0) fin = NEGF;
    if (lane == 0) {
        float loss = (L > 0) ? -fin * LN2_ : 0.0f;
        if (!(loss < 1e29f)) loss = 0.0f;
        losses[b] = loss;
    }
}

__global__ __launch_bounds__(64) void finalize_k(const float* __restrict__ losses,
                                                 const int* __restrict__ gid,
                                                 float* __restrict__ out) {
    int lane = threadIdx.x;
    float l = losses[lane];
    int g = gid[lane];
    float s = l;
    float s0 = (g == 0) ? l : 0.0f, c0 = (g == 0) ? 1.0f : 0.0f;
    float s1 = (g == 1) ? l : 0.0f, c1 = (g == 1) ? 1.0f : 0.0f;
    for (int off = 32; off; off >>= 1) {
        s  += __shfl_xor(s, off);
        s0 += __shfl_xor(s0, off);
        c0 += __shfl_xor(c0, off);
        s1 += __shfl_xor(s1, off);
        c1 += __shfl_xor(c1, off);
    }
    if (lane == 0) {
        float base = s * (1.0f / B_);
        float m0 = s0 / fmaxf(c0, 1.0f);
        float m1 = s1 / fmaxf(c1, 1.0f);
        float mean = 0.5f * (m0 + m1);
        float var = (m0 - mean) * (m0 - mean) + (m1 - mean) * (m1 - mean); // ddof=1, N=2
        out[0] = base + 0.5f * var;
        out[1] = base;
        out[2] = var;
    }
}

extern "C" void kernel_launch(void* const* d_in, const int* in_sizes, int n_in,
                              void* d_out, int out_size, void* d_ws, size_t ws_size,
                              hipStream_t stream) {
    const float* lp = (const float*)d_in[0];
    const int* targets = (const int*)d_in[1];
    const int* ilen = (const int*)d_in[2];
    const int* tlen = (const int*)d_in[3];
    const int* gid = (const int*)d_in[4];
    float* out = (float*)d_out;

    char* ws = (char*)d_ws;
    int* tgt_full = (int*)ws;                         // 16 KB
    float* losses = (float*)(ws + 16384);             // 256 B
    float* em4f = (float*)(ws + 32768);               // 64*250*64*16 B = 16.38 MB
    size_t need = 32768 + (size_t)B_ * T4_ * 64 * 16;

    prep_tgt_k<<<1, 64, 0, stream>>>(targets, tlen, tgt_full);
    if (ws_size >= need) {
        gather_k<<<B_ * T4_, 256, 0, stream>>>(lp, tgt_full, ilen, em4f);
        ctc_rec_k<<<B_, 64, 0, stream>>>((const float4*)em4f, tgt_full, ilen, tlen, losses);
    } else {
        ctc_rec_direct_k<<<B_, 64, 0, stream>>>(lp, tgt_full, ilen, tlen, losses);
    }
    finalize_k<<<1, 64, 0, stream>>>(losses, gid, out);
}

// Round 7
// 107.917 us; speedup vs baseline: 2.8054x; 1.0796x over previous
//
#include <hip/hip_runtime.h>

#define T_ 1000
#define T4_ 250
#define B_ 64
#define V_ 1024
#define LMAX_ 64
#define NEGF (-1e30f)
#define LOG2E_ 1.4426950408889634f
#define LN2_ 0.6931471805599453f

__device__ __forceinline__ float ex2(float x) { return __builtin_amdgcn_exp2f(x); }
__device__ __forceinline__ float lg2(float x) { return __builtin_amdgcn_logf(x); }
__device__ __forceinline__ float rlane(float x, int l) {
    return __int_as_float(__builtin_amdgcn_readlane(__float_as_int(x), l));
}
#define FENCE_ __builtin_amdgcn_sched_barrier(0)

// Q4(u) ~= log2(1+u) on [0,2]; Newton interp at {0,.5,1,1.5,2}; |err| <= ~2e-3.
// Q4(1)=1 and Q4(2)=log2(3) exact by construction.
__device__ __forceinline__ float Q4(float u) {
    return u * (1.412361f + u * (-0.571582f + u * (0.187621f - 0.028400f * u)));
}
// lae2 in log2 domain via exp2 + poly (no v_log): max + log2(1 + 2^(min-max))
__device__ __forceinline__ float lae2p(float x, float y) {
    float m = fmaxf(x, y);
    float p = ex2(fminf(x, y) - m);
    return m + Q4(p);
}

__global__ void prep_tgt_k(const int* __restrict__ targets,
                           const int* __restrict__ tlen,
                           int* __restrict__ tgt_full) {
    int b = threadIdx.x;
    if (b >= B_) return;
    int off = 0;
    for (int i = 0; i < b; ++i) off += tlen[i];
    int L = tlen[b];
    for (int l = 0; l < LMAX_; ++l)
        tgt_full[b * LMAX_ + l] = (l < L) ? targets[off + l] : 0;
}

// em4[((b*250+t4)*64+lane)*4 + (t&3)] = log2e * lp[t, b, lane<63 ? tgt[lane] : BLANK]
__global__ __launch_bounds__(256) void gather_k(const float* __restrict__ lp,
                                                const int* __restrict__ tgt_full,
                                                const int* __restrict__ ilen,
                                                float* __restrict__ em4f) {
    int t4 = blockIdx.x % T4_;
    int b = blockIdx.x / T4_;
    int tl = threadIdx.x >> 6;
    int i = threadIdx.x & 63;
    int t = t4 * 4 + tl;
    if (t >= ilen[b]) return;
    int col = (i == 63) ? 0 : tgt_full[b * LMAX_ + i];
    const float* row = lp + (size_t)t * (B_ * V_) + (size_t)b * V_;
    em4f[(((size_t)b * T4_ + t4) * 64 + i) * 4 + tl] = row[col] * LOG2E_;
}

// One wave per sample. Lane i owns states 2i (blank) and 2i+1 (label i). L<=63.
__global__ __launch_bounds__(64) void ctc_rec_k(const float4* __restrict__ em4,
                                                const int* __restrict__ tgt_full,
                                                const int* __restrict__ ilen,
                                                const int* __restrict__ tlen,
                                                float* __restrict__ losses) {
    int b = blockIdx.x, lane = threadIdx.x;
    int L = tlen[b], Tin = ilen[b], Te = Tin - 1;
    int tg = tgt_full[b * LMAX_ + lane];
    int tgp = __shfl_up(tg, 1);
    bool skip1 = (lane >= 1) && (tg != 0) && (tg != tgp);
    bool row0 = (lane & 15) == 0;
    bool is16 = (lane == 16), is32 = (lane == 32), is48 = (lane == 48);
    const float4* e4 = em4 + (size_t)b * (T4_ * 64) + lane;
    int Gc = Te >> 2;
    if (Gc < 0) Gc = 0;
    if (Gc > T4_ - 1) Gc = T4_ - 1;
    float a0 = NEGF, a1 = NEGF;

    auto ldE = [&](int g) -> float4 {
        int gm = g < Gc ? g : Gc;
        return e4[(size_t)gm * 64];
    };
    // p1m[lane] = a1[lane-1], p1m[0] = NEGF. row_shr:1 + readlane fixups at rows.
    auto shr1 = [&](float x) -> float {
        int xi = __float_as_int(x);
        float sh = __int_as_float(
            __builtin_amdgcn_update_dpp(__float_as_int(NEGF), xi, 0x111, 0xF, 0xF, false));
        float v15 = rlane(x, 15), v31 = rlane(x, 31), v47 = rlane(x, 47);
        float bval = is16 ? v15 : (is32 ? v31 : (is48 ? v47 : NEGF));
        return row0 ? bval : sh;
    };
    // even: a0' = lae(a0, p1m) + xb;  odd: a1' = lae3(a1,a0,sk)+xe = lae(a1, w)+xe,
    // w = skip1 ? lae(a0,p1m) : a0  (shares u with the even update).
    auto step = [&](float xb, float xe) {
        float p1m = shr1(a1);
        float u = lae2p(a0, p1m);
        float w = skip1 ? u : a0;
        a0 = u + xb;
        a1 = lae2p(a1, w) + xe;
    };

    if (Te >= 35) {
        float4 S0 = ldE(0), S1 = ldE(1), S2 = ldE(2), S3 = ldE(3);
        float4 S4 = ldE(4), S5 = ldE(5), S6 = ldE(6), S7 = ldE(7);
        FENCE_;
        a0 = (lane == 0) ? rlane(S0.x, 63) : NEGF;
        a1 = (lane == 0 && L > 0) ? S0.x : NEGF;
        step(rlane(S0.y, 63), S0.y); step(rlane(S0.z, 63), S0.z); step(rlane(S0.w, 63), S0.w);
        S0 = ldE(8);
        FENCE_;
#define SUBF(S, G) do {                                                        \
        float xb0_ = rlane(S.x, 63), xb1_ = rlane(S.y, 63);                    \
        float xb2_ = rlane(S.z, 63), xb3_ = rlane(S.w, 63);                    \
        step(xb0_, S.x); step(xb1_, S.y); step(xb2_, S.z); step(xb3_, S.w);    \
        S = ldE((G) + 8);                                                      \
        FENCE_;                                                                \
    } while (0)
        SUBF(S1, 1); SUBF(S2, 2); SUBF(S3, 3); SUBF(S4, 4);
        SUBF(S5, 5); SUBF(S6, 6); SUBF(S7, 7);
        int c = 1;
        for (; 32 * c + 31 <= Te; ++c) {
            int g0 = 8 * c;
            SUBF(S0, g0 + 0); SUBF(S1, g0 + 1); SUBF(S2, g0 + 2); SUBF(S3, g0 + 3);
            SUBF(S4, g0 + 4); SUBF(S5, g0 + 5); SUBF(S6, g0 + 6); SUBF(S7, g0 + 7);
        }
#undef SUBF
        int tb = 32 * c;
#define SUBT(S, T0) do {                                                       \
        float xb0_ = rlane(S.x, 63), xb1_ = rlane(S.y, 63);                    \
        float xb2_ = rlane(S.z, 63), xb3_ = rlane(S.w, 63);                    \
        if ((T0) + 0 <= Te) step(xb0_, S.x);                                   \
        if ((T0) + 1 <= Te) step(xb1_, S.y);                                   \
        if ((T0) + 2 <= Te) step(xb2_, S.z);                                   \
        if ((T0) + 3 <= Te) step(xb3_, S.w);                                   \
    } while (0)
        SUBT(S0, tb + 0);  SUBT(S1, tb + 4);  SUBT(S2, tb + 8);  SUBT(S3, tb + 12);
        SUBT(S4, tb + 16); SUBT(S5, tb + 20); SUBT(S6, tb + 24); SUBT(S7, tb + 28);
#undef SUBT
    } else {
        // small-Te safety path (never hit: Tin >= 500)
        float4 E0 = e4[0];
        a0 = (lane == 0) ? rlane(E0.x, 63) : NEGF;
        a1 = (lane == 0 && L > 0) ? E0.x : NEGF;
        for (int g = 0; 4 * g <= Te; ++g) {
            int gm = g < Gc ? g : Gc;
            float4 E = e4[(size_t)gm * 64];
            if (4 * g + 0 <= Te && 4 * g + 0 >= 1) step(rlane(E.x, 63), E.x);
            if (4 * g + 1 <= Te && 4 * g + 1 >= 1) step(rlane(E.y, 63), E.y);
            if (4 * g + 2 <= Te && 4 * g + 2 >= 1) step(rlane(E.z, 63), E.z);
            if (4 * g + 3 <= Te && 4 * g + 3 >= 1) step(rlane(E.w, 63), E.w);
        }
    }

    // end_ll at t = Tin-1 (log2 domain, exact lae once)
    int lidx = (L > 0) ? (L - 1) : 0;
    float aPrev = __shfl(a1, lidx);
    float aLast = __shfl(a0, (L < 63) ? L : 63);   // state 2L (blank), L<=63
    float x = aLast, y = (L > 0) ? aPrev : NEGF;
    float m = fmaxf(x, y), d = fminf(x, y) - m;
    float fin = m + lg2(1.0f + ex2(d));
    if (Tin <= 0) fin = NEGF;
    if (lane == 0) {
        float loss = (L > 0) ? -fin * LN2_ : 0.0f;
        if (!(loss < 1e29f)) loss = 0.0f;          // zero_infinity (NaN-safe)
        losses[b] = loss;
    }
}

// Fallback when ws too small: per-step scattered loads (slow, correct).
__global__ __launch_bounds__(64) void ctc_rec_direct_k(const float* __restrict__ lp,
                                                       const int* __restrict__ tgt_full,
                                                       const int* __restrict__ ilen,
                                                       const int* __restrict__ tlen,
                                                       float* __restrict__ losses) {
    int b = blockIdx.x, lane = threadIdx.x;
    int L = tlen[b], Tin = ilen[b], Te = Tin - 1;
    int tg = tgt_full[b * LMAX_ + lane];
    int tgp = __shfl_up(tg, 1);
    bool skip1 = (lane >= 1) && (tg != 0) && (tg != tgp);
    bool row0 = (lane & 15) == 0;
    bool is16 = (lane == 16), is32 = (lane == 32), is48 = (lane == 48);
    int col = (lane == 63) ? 0 : tg;
    const float* src = lp + (size_t)b * V_;
    const long long stride = (long long)B_ * V_;
    float a0 = NEGF, a1 = NEGF;
    auto shr1 = [&](float x) -> float {
        int xi = __float_as_int(x);
        float sh = __int_as_float(
            __builtin_amdgcn_update_dpp(__float_as_int(NEGF), xi, 0x111, 0xF, 0xF, false));
        float v15 = rlane(x, 15), v31 = rlane(x, 31), v47 = rlane(x, 47);
        float bval = is16 ? v15 : (is32 ? v31 : (is48 ? v47 : NEGF));
        return row0 ? bval : sh;
    };
    auto step = [&](float xb, float xe) {
        float p1m = shr1(a1);
        float u = lae2p(a0, p1m);
        float w = skip1 ? u : a0;
        a0 = u + xb;
        a1 = lae2p(a1, w) + xe;
    };
    if (Tin >= 1) {
        float e = src[col] * LOG2E_;
        a0 = (lane == 0) ? rlane(e, 63) : NEGF;
        a1 = (lane == 0 && L > 0) ? e : NEGF;
        for (int t = 1; t <= Te; ++t) {
            float xe = src[(long long)t * stride + col] * LOG2E_;
            step(rlane(xe, 63), xe);
        }
    }
    int lidx = (L > 0) ? (L - 1) : 0;
    float aPrev = __shfl(a1, lidx);
    float aLast = __shfl(a0, (L < 63) ? L : 63);
    float x = aLast, y = (L > 0) ? aPrev : NEGF;
    float m = fmaxf(x, y), d = fminf(x, y) - m;
    float fin = m + lg2(1.0f + ex2(d));
    if (Tin <= 0) fin = NEGF;
    if (lane == 0) {
        float loss = (L > 0) ? -fin * LN2_ : 0.0f;
        if (!(loss < 1e29f)) loss = 0.0f;
        losses[b] = loss;
    }
}

__global__ __launch_bounds__(64) void finalize_k(const float* __restrict__ losses,
                                                 const int* __restrict__ gid,
                                                 float* __restrict__ out) {
    int lane = threadIdx.x;
    float l = losses[lane];
    int g = gid[lane];
    float s = l;
    float s0 = (g == 0) ? l : 0.0f, c0 = (g == 0) ? 1.0f : 0.0f;
    float s1 = (g == 1) ? l : 0.0f, c1 = (g == 1) ? 1.0f : 0.0f;
    for (int off = 32; off; off >>= 1) {
        s  += __shfl_xor(s, off);
        s0 += __shfl_xor(s0, off);
        c0 += __shfl_xor(c0, off);
        s1 += __shfl_xor(s1, off);
        c1 += __shfl_xor(c1, off);
    }
    if (lane == 0) {
        float base = s * (1.0f / B_);
        float m0 = s0 / fmaxf(c0, 1.0f);
        float m1 = s1 / fmaxf(c1, 1.0f);
        float mean = 0.5f * (m0 + m1);
        float var = (m0 - mean) * (m0 - mean) + (m1 - mean) * (m1 - mean); // ddof=1, N=2
        out[0] = base + 0.5f * var;
        out[1] = base;
        out[2] = var;
    }
}

extern "C" void kernel_launch(void* const* d_in, const int* in_sizes, int n_in,
                              void* d_out, int out_size, void* d_ws, size_t ws_size,
                              hipStream_t stream) {
    const float* lp = (const float*)d_in[0];
    const int* targets = (const int*)d_in[1];
    const int* ilen = (const int*)d_in[2];
    const int* tlen = (const int*)d_in[3];
    const int* gid = (const int*)d_in[4];
    float* out = (float*)d_out;

    char* ws = (char*)d_ws;
    int* tgt_full = (int*)ws;                         // 16 KB
    float* losses = (float*)(ws + 16384);             // 256 B
    float* em4f = (float*)(ws + 32768);               // 64*250*64*16 B = 16.38 MB
    size_t need = 32768 + (size_t)B_ * T4_ * 64 * 16;

    prep_tgt_k<<<1, 64, 0, stream>>>(targets, tlen, tgt_full);
    if (ws_size >= need) {
        gather_k<<<B_ * T4_, 256, 0, stream>>>(lp, tgt_full, ilen, em4f);
        ctc_rec_k<<<B_, 64, 0, stream>>>((const float4*)em4f, tgt_full, ilen, tlen, losses);
    } else {
        ctc_rec_direct_k<<<B_, 64, 0, stream>>>(lp, tgt_full, ilen, tlen, losses);
    }
    finalize_k<<<1, 64, 0, stream>>>(losses, gid, out);
}